// Round 4
// baseline (506.217 us; speedup 1.0000x reference)
//
#include <hip/hip_runtime.h>
#include <math.h>

// ---- problem constants ----
constexpr int kH    = 1024;
constexpr int kZ    = 1024;
constexpr int kA    = 4;
constexpr int kF    = 30;
constexpr int kDIN  = 2048;
constexpr int kDH   = 512;
constexpr int kEIN  = 1118;
constexpr int kEH   = 512;
constexpr int kEOUT = 94;

// fused kernel geometry (uniform 512-thread blocks)
constexpr int GRU_NB = 64;                    // barrier participants, bid 0..63
constexpr int ZB0    = GRU_NB;                // 120 z-half blocks   [64,184)
constexpr int EV0    = ZB0 + kF * 4;          // 8 eval blocks       [184,192)
constexpr int HB0    = EV0 + 8;               // 120 agru-half blocks[192,312)
constexpr int NBLK   = HB0 + kF * 4;          // 312

// workspace layout (floats)
constexpr size_t AGRU_OFF = 0;                              // kF*kH      = 30720
constexpr size_t HACC_OFF = AGRU_OFF + (size_t)kF * kH;     // kF*2*kDH   = 30720
constexpr size_t EHA_OFF  = HACC_OFF + (size_t)kF * 2 * kDH;// kEH        = 512
constexpr size_t FLG_OFF  = EHA_OFF + kEH;                  // 64*32 u32  = 2048
constexpr size_t ZERO_CNT = (size_t)kF * 2 * kDH + kEH + GRU_NB * 32;

__device__ __forceinline__ float sigmoidf_(float x) { return 1.0f / (1.0f + __expf(-x)); }

__device__ __forceinline__ float wave_reduce(float v) {
#pragma unroll
  for (int off = 32; off > 0; off >>= 1) v += __shfl_down(v, off, 64);
  return v;
}

__device__ __forceinline__ float agent_ld(const float* p) {
  return __hip_atomic_load(p, __ATOMIC_RELAXED, __HIP_MEMORY_SCOPE_AGENT);
}

// wave0 polls all 64 per-block flags (one per lane) until all >= tgt
__device__ __forceinline__ void wait_flags(const unsigned* flags, int lane, unsigned tgt) {
  for (;;) {
    unsigned v = __hip_atomic_load(&flags[lane * 32], __ATOMIC_RELAXED,
                                   __HIP_MEMORY_SCOPE_AGENT);
    if (__all(v >= tgt)) break;
    __builtin_amdgcn_s_sleep(1);
  }
  __builtin_amdgcn_fence(__ATOMIC_ACQUIRE, "agent");
}

__global__ __launch_bounds__(512) void fused1(
    const float* __restrict__ Whh, const float* __restrict__ bhh,
    const float* __restrict__ Wih, const float* __restrict__ bih,
    const float* __restrict__ a_t, const float* __restrict__ b_t,
    const float* __restrict__ zpos, const float* __restrict__ zneg,
    const float* __restrict__ W1, const float* __restrict__ ipo,
    const float* __restrict__ eW1,
    float* __restrict__ agru, float* __restrict__ hacc,
    float* __restrict__ ehacc, unsigned* __restrict__ flags,
    const int* __restrict__ fptr) {
  const int bid  = blockIdx.x;
  const int tid  = threadIdx.x;
  const int wave = tid >> 6;
  const int lane = tid & 63;
  const int f    = *fptr;

  __shared__ float gis[kF][16][3];
  __shared__ __align__(16) float hs[kH];
  __shared__ float xs_p[256];
  __shared__ float xs_n[256];
  __shared__ float evs[140];

  if (bid < GRU_NB) {
    // ---------------- GRU: 16 hidden rows per block, 2 per wave ----------------
    const int jb = bid * 16;
    const int j0 = jb + wave;       // rows j0 and j1 = j0+8
    const int j1 = jb + wave + 8;
    const float4* W4 = (const float4*)Whh;
    float4 wr0[4], wz0[4], wn0[4], wr1[4], wz1[4], wn1[4];
#pragma unroll
    for (int i = 0; i < 4; i++) {
      wr0[i] = W4[(size_t)j0 * 256 + i * 64 + lane];
      wz0[i] = W4[(size_t)(j0 + kH) * 256 + i * 64 + lane];
      wn0[i] = W4[(size_t)(j0 + 2 * kH) * 256 + i * 64 + lane];
      wr1[i] = W4[(size_t)j1 * 256 + i * 64 + lane];
      wz1[i] = W4[(size_t)(j1 + kH) * 256 + i * 64 + lane];
      wn1[i] = W4[(size_t)(j1 + 2 * kH) * 256 + i * 64 + lane];
    }
    const float b0r = bhh[j0], b0z = bhh[j0 + kH], b0n = bhh[j0 + 2 * kH];
    const float b1r = bhh[j1], b1z = bhh[j1 + kH], b1n = bhh[j1 + 2 * kH];

    // gi[t][w][g] for this block's 16 rows
    for (int idx = tid; idx < kF * 16 * 3; idx += 512) {
      int t = idx / 48;
      int rem = idx - t * 48;
      int w = rem / 3, g = rem - w * 3;
      int r = jb + w + g * kH;
      float acc = bih[r];
      const float* wih = Wih + (size_t)r * kA;
      const float* at  = a_t + (size_t)t * kA;
#pragma unroll
      for (int k = 0; k < kA; k++) acc += wih[k] * at[k];
      gis[t][w][g] = acc;
    }
    __syncthreads();

    const float4* hs4 = (const float4*)hs;
    for (int t = 0; t < f; t++) {
      const float* hsrc = (t == 0) ? b_t : (agru + (size_t)(t - 1) * kH);
      hs[tid]       = agent_ld(hsrc + tid);
      hs[tid + 512] = agent_ld(hsrc + tid + 512);
      __syncthreads();

      float a0r = 0.f, a0z = 0.f, a0n = 0.f, a1r = 0.f, a1z = 0.f, a1n = 0.f;
#pragma unroll
      for (int i = 0; i < 4; i++) {
        float4 h4 = hs4[i * 64 + lane];
        a0r += wr0[i].x * h4.x + wr0[i].y * h4.y + wr0[i].z * h4.z + wr0[i].w * h4.w;
        a0z += wz0[i].x * h4.x + wz0[i].y * h4.y + wz0[i].z * h4.z + wz0[i].w * h4.w;
        a0n += wn0[i].x * h4.x + wn0[i].y * h4.y + wn0[i].z * h4.z + wn0[i].w * h4.w;
        a1r += wr1[i].x * h4.x + wr1[i].y * h4.y + wr1[i].z * h4.z + wr1[i].w * h4.w;
        a1z += wz1[i].x * h4.x + wz1[i].y * h4.y + wz1[i].z * h4.z + wz1[i].w * h4.w;
        a1n += wn1[i].x * h4.x + wn1[i].y * h4.y + wn1[i].z * h4.z + wn1[i].w * h4.w;
      }
      a0r = wave_reduce(a0r); a0z = wave_reduce(a0z); a0n = wave_reduce(a0n);
      a1r = wave_reduce(a1r); a1z = wave_reduce(a1z); a1n = wave_reduce(a1n);

      if (lane == 0) {
        float rg = sigmoidf_(gis[t][wave][0] + a0r + b0r);
        float zg = sigmoidf_(gis[t][wave][1] + a0z + b0z);
        float ng = tanhf(gis[t][wave][2] + rg * (a0n + b0n));
        __hip_atomic_store(agru + (size_t)t * kH + j0,
                           (1.0f - zg) * ng + zg * hs[j0],
                           __ATOMIC_RELAXED, __HIP_MEMORY_SCOPE_AGENT);
        rg = sigmoidf_(gis[t][wave + 8][0] + a1r + b1r);
        zg = sigmoidf_(gis[t][wave + 8][1] + a1z + b1z);
        ng = tanhf(gis[t][wave + 8][2] + rg * (a1n + b1n));
        __hip_atomic_store(agru + (size_t)t * kH + j1,
                           (1.0f - zg) * ng + zg * hs[j1],
                           __ATOMIC_RELAXED, __HIP_MEMORY_SCOPE_AGENT);
      }
      __syncthreads();  // drain stores (vmcnt0) before release
      if (tid == 0) {
        __threadfence();
        __hip_atomic_store(&flags[bid * 32], (unsigned)(t + 1),
                           __ATOMIC_RELEASE, __HIP_MEMORY_SCOPE_AGENT);
      }
      if (wave == 0) wait_flags(flags, lane, (unsigned)(t + 1));
      __syncthreads();
    }
  } else if (bid < EV0) {
    // ---------------- expert first layer, z-half (no GRU dependency) ----------------
    int idx = bid - ZB0;
    int e = idx >> 2, part = idx & 3;
    if (e >= f) return;
    int r0 = part * 256;
    if (tid < 256) {
      xs_p[tid] = zpos[(size_t)e * kZ + r0 + tid];
      xs_n[tid] = zneg[(size_t)e * kZ + r0 + tid];
    }
    __syncthreads();
    float ap = 0.f, an = 0.f;
    const float* w = W1 + ((size_t)e * kDIN + r0) * kDH + tid;
#pragma unroll 4
    for (int r = 0; r < 256; r++) {
      float wv = w[(size_t)r * kDH];
      ap += xs_p[r] * wv;
      an += xs_n[r] * wv;
    }
    atomicAdd(&hacc[((size_t)e * 2 + 0) * kDH + tid], ap);
    atomicAdd(&hacc[((size_t)e * 2 + 1) * kDH + tid], an);
  } else if (bid < HB0) {
    // ---------------- eval first layer (no GRU dependency) ----------------
    int part = bid - EV0;  // 0..7
    int r0 = part * 140;
    int nr = min(140, kEIN - r0);
    if (tid < nr) {
      int r = r0 + tid;
      evs[tid] = (r < kH) ? b_t[r] : ipo[r - kH];
    }
    __syncthreads();
    float acc = 0.f;
    const float* w = eW1 + (size_t)r0 * kEH + tid;
    for (int r = 0; r < nr; r++) acc += evs[r] * w[(size_t)r * kEH];
    atomicAdd(&ehacc[tid], acc);
  } else {
    // ---------------- expert first layer, agru-half (waits for step e) ----------------
    int idx = bid - HB0;
    int e = idx >> 2, part = idx & 3;
    if (e >= f) return;
    if (wave == 0) wait_flags(flags, lane, (unsigned)(e + 1));
    __syncthreads();
    int r0 = part * 256;
    if (tid < 256) xs_p[tid] = agent_ld(agru + (size_t)e * kH + r0 + tid);
    __syncthreads();
    float a = 0.f;
    const float* w = W1 + ((size_t)e * kDIN + kZ + r0) * kDH + tid;
#pragma unroll 4
    for (int r = 0; r < 256; r++) a += xs_p[r] * w[(size_t)r * kDH];
    atomicAdd(&hacc[((size_t)e * 2 + 0) * kDH + tid], a);
    atomicAdd(&hacc[((size_t)e * 2 + 1) * kDH + tid], a);
  }
}

// ---------------- stage2: second layers -> 2f+94 outputs ----------------
__global__ __launch_bounds__(512) void stage2(const float* __restrict__ hacc,
                                              const float* __restrict__ ehacc,
                                              const float* __restrict__ b1,
                                              const float* __restrict__ W2,
                                              const float* __restrict__ b2,
                                              const float* __restrict__ eb1,
                                              const float* __restrict__ eW2,
                                              const float* __restrict__ eb2,
                                              float* __restrict__ out,
                                              const int* __restrict__ fptr) {
  int b = blockIdx.x;
  int tid = threadIdx.x;
  int f = *fptr;
  if (b < kF) {
    int i = b;
    if (i >= f) return;
    float bias = b1[(size_t)i * kDH + tid];
    float hp = fmaxf(hacc[((size_t)i * 2 + 0) * kDH + tid] + bias, 0.f);
    float hn = fmaxf(hacc[((size_t)i * 2 + 1) * kDH + tid] + bias, 0.f);
    float w = W2[(size_t)i * kDH + tid];
    float pp = wave_reduce(hp * w);
    float pn = wave_reduce(hn * w);
    __shared__ float redp[8];
    __shared__ float redn[8];
    int wave = tid >> 6, lane = tid & 63;
    if (lane == 0) { redp[wave] = pp; redn[wave] = pn; }
    __syncthreads();
    if (tid == 0) {
      float sp = 0.f, sn = 0.f;
#pragma unroll
      for (int k = 0; k < 8; k++) { sp += redp[k]; sn += redn[k]; }
      out[i] = sp + b2[i];
      out[f + i] = sn + b2[i];
    }
  } else {
    if (tid < kEOUT) {
      float acc = eb2[tid];
      for (int h = 0; h < kEH; h++) {
        float eh = fmaxf(ehacc[h] + eb1[h], 0.f);
        acc += eh * eW2[(size_t)h * kEOUT + tid];
      }
      out[2 * f + tid] = sigmoidf_(acc);
    }
  }
}

extern "C" void kernel_launch(void* const* d_in, const int* in_sizes, int n_in,
                              void* d_out, int out_size, void* d_ws, size_t ws_size,
                              hipStream_t stream) {
  const float* b_t  = (const float*)d_in[0];
  const float* a_t  = (const float*)d_in[1];
  const float* zpos = (const float*)d_in[2];
  const float* zneg = (const float*)d_in[3];
  const float* ipo  = (const float*)d_in[4];
  const float* gWih = (const float*)d_in[5];
  const float* gWhh = (const float*)d_in[6];
  const float* gbih = (const float*)d_in[7];
  const float* gbhh = (const float*)d_in[8];
  const float* mW1  = (const float*)d_in[9];
  const float* mb1  = (const float*)d_in[10];
  const float* mW2  = (const float*)d_in[11];
  const float* mb2  = (const float*)d_in[12];
  const float* eW1  = (const float*)d_in[13];
  const float* eb1  = (const float*)d_in[14];
  const float* eW2  = (const float*)d_in[15];
  const float* eb2  = (const float*)d_in[16];
  const int*   fptr = (const int*)d_in[17];

  float* ws     = (float*)d_ws;
  float* agru   = ws + AGRU_OFF;
  float* hacc   = ws + HACC_OFF;
  float* ehacc  = ws + EHA_OFF;
  unsigned* flg = (unsigned*)(ws + FLG_OFF);
  float* out    = (float*)d_out;

  // zero accumulators + flags (contiguous)
  hipMemsetAsync(hacc, 0, ZERO_CNT * sizeof(float), stream);

  fused1<<<NBLK, 512, 0, stream>>>(gWhh, gbhh, gWih, gbih, a_t, b_t, zpos, zneg,
                                   mW1, ipo, eW1, agru, hacc, ehacc, flg, fptr);

  stage2<<<kF + 1, 512, 0, stream>>>(hacc, ehacc, mb1, mW2, mb2, eb1, eW2, eb2, out, fptr);
}

// Round 5
// 355.028 us; speedup vs baseline: 1.4259x; 1.4259x over previous
//
#include <hip/hip_runtime.h>
#include <math.h>

// ---- problem constants ----
constexpr int kH    = 1024;
constexpr int kZ    = 1024;
constexpr int kA    = 4;
constexpr int kF    = 30;
constexpr int kDIN  = 2048;
constexpr int kDH   = 512;
constexpr int kEIN  = 1118;
constexpr int kEH   = 512;
constexpr int kEOUT = 94;

constexpr int GRU_NB  = 64;   // GRU blocks (barrier participants)
constexpr int EXP_PRT = 8;    // partial-sum splits per expert (256 K-rows each)

// workspace layout (floats)
constexpr size_t AGRU_OFF = 0;                                   // kF*kH
constexpr size_t HACC_OFF = AGRU_OFF + (size_t)kF * kH;          // kF*2*8*kDH
constexpr size_t EHA_OFF  = HACC_OFF + (size_t)kF * 2 * EXP_PRT * kDH;  // 8*kEH
constexpr size_t FLG_OFF  = EHA_OFF + (size_t)8 * kEH;           // 64*32 u32
constexpr size_t FLG_CNT  = (size_t)GRU_NB * 32;

__device__ __forceinline__ float sigmoidf_(float x) { return 1.0f / (1.0f + __expf(-x)); }

__device__ __forceinline__ float wave_reduce(float v) {
#pragma unroll
  for (int off = 32; off > 0; off >>= 1) v += __shfl_down(v, off, 64);
  return v;
}

// agent-scope (sc1) load/store: operate at the coherent point (L3), bypass
// the per-XCD L2 -> no wbl2/inv fences needed anywhere.
__device__ __forceinline__ float agent_ld(const float* p) {
  return __hip_atomic_load(p, __ATOMIC_RELAXED, __HIP_MEMORY_SCOPE_AGENT);
}
__device__ __forceinline__ void agent_st(float* p, float v) {
  __hip_atomic_store(p, v, __ATOMIC_RELAXED, __HIP_MEMORY_SCOPE_AGENT);
}

// ---------------- GRU: 64 blocks, runs ALONE (no co-resident streamers) ----------------
__global__ __launch_bounds__(512) void gru64(const float* __restrict__ Whh,
                                             const float* __restrict__ bhh,
                                             const float* __restrict__ Wih,
                                             const float* __restrict__ bih,
                                             const float* __restrict__ a_t,
                                             const float* __restrict__ b_t,
                                             float* __restrict__ agru,
                                             unsigned* __restrict__ flags,
                                             const int* __restrict__ fptr) {
  const int bid  = blockIdx.x;
  const int tid  = threadIdx.x;
  const int wave = tid >> 6;
  const int lane = tid & 63;
  const int f    = *fptr;

  const int jb = bid * 16;
  const int j0 = jb + wave;       // rows j0 and j1 = j0+8
  const int j1 = jb + wave + 8;

  __shared__ float gis[kF][16][3];
  __shared__ __align__(16) float hs[kH];

  const float4* W4 = (const float4*)Whh;
  float4 wr0[4], wz0[4], wn0[4], wr1[4], wz1[4], wn1[4];
#pragma unroll
  for (int i = 0; i < 4; i++) {
    wr0[i] = W4[(size_t)j0 * 256 + i * 64 + lane];
    wz0[i] = W4[(size_t)(j0 + kH) * 256 + i * 64 + lane];
    wn0[i] = W4[(size_t)(j0 + 2 * kH) * 256 + i * 64 + lane];
    wr1[i] = W4[(size_t)j1 * 256 + i * 64 + lane];
    wz1[i] = W4[(size_t)(j1 + kH) * 256 + i * 64 + lane];
    wn1[i] = W4[(size_t)(j1 + 2 * kH) * 256 + i * 64 + lane];
  }
  const float b0r = bhh[j0], b0z = bhh[j0 + kH], b0n = bhh[j0 + 2 * kH];
  const float b1r = bhh[j1], b1z = bhh[j1 + kH], b1n = bhh[j1 + 2 * kH];

  // gi[t][w][g] for this block's 16 rows (off critical path)
  for (int idx = tid; idx < kF * 16 * 3; idx += 512) {
    int t = idx / 48;
    int rem = idx - t * 48;
    int w = rem / 3, g = rem - w * 3;
    int r = jb + w + g * kH;
    float acc = bih[r];
    const float* wih = Wih + (size_t)r * kA;
    const float* at  = a_t + (size_t)t * kA;
#pragma unroll
    for (int k = 0; k < kA; k++) acc += wih[k] * at[k];
    gis[t][w][g] = acc;
  }
  __syncthreads();

  const float4* hs4 = (const float4*)hs;
  for (int t = 0; t < f; t++) {
    const float* hsrc = (t == 0) ? b_t : (agru + (size_t)(t - 1) * kH);
    hs[tid]       = agent_ld(hsrc + tid);
    hs[tid + 512] = agent_ld(hsrc + tid + 512);
    __syncthreads();

    float a0r = 0.f, a0z = 0.f, a0n = 0.f, a1r = 0.f, a1z = 0.f, a1n = 0.f;
#pragma unroll
    for (int i = 0; i < 4; i++) {
      float4 h4 = hs4[i * 64 + lane];
      a0r += wr0[i].x * h4.x + wr0[i].y * h4.y + wr0[i].z * h4.z + wr0[i].w * h4.w;
      a0z += wz0[i].x * h4.x + wz0[i].y * h4.y + wz0[i].z * h4.z + wz0[i].w * h4.w;
      a0n += wn0[i].x * h4.x + wn0[i].y * h4.y + wn0[i].z * h4.z + wn0[i].w * h4.w;
      a1r += wr1[i].x * h4.x + wr1[i].y * h4.y + wr1[i].z * h4.z + wr1[i].w * h4.w;
      a1z += wz1[i].x * h4.x + wz1[i].y * h4.y + wz1[i].z * h4.z + wz1[i].w * h4.w;
      a1n += wn1[i].x * h4.x + wn1[i].y * h4.y + wn1[i].z * h4.z + wn1[i].w * h4.w;
    }
    a0r = wave_reduce(a0r); a0z = wave_reduce(a0z); a0n = wave_reduce(a0n);
    a1r = wave_reduce(a1r); a1z = wave_reduce(a1z); a1n = wave_reduce(a1n);

    if (lane == 0) {
      float rg = sigmoidf_(gis[t][wave][0] + a0r + b0r);
      float zg = sigmoidf_(gis[t][wave][1] + a0z + b0z);
      float ng = tanhf(gis[t][wave][2] + rg * (a0n + b0n));
      agent_st(agru + (size_t)t * kH + j0, (1.0f - zg) * ng + zg * hs[j0]);
      rg = sigmoidf_(gis[t][wave + 8][0] + a1r + b1r);
      zg = sigmoidf_(gis[t][wave + 8][1] + a1z + b1z);
      ng = tanhf(gis[t][wave + 8][2] + rg * (a1n + b1n));
      agent_st(agru + (size_t)t * kH + j1, (1.0f - zg) * ng + zg * hs[j1]);
    }
    // ack h stores at the coherence point before publishing the flag
    asm volatile("s_waitcnt vmcnt(0)" ::: "memory");
    __syncthreads();
    if (tid == 0) {
      __hip_atomic_store(&flags[bid * 32], (unsigned)(t + 1),
                         __ATOMIC_RELAXED, __HIP_MEMORY_SCOPE_AGENT);
    }
    if (wave == 0) {
      const unsigned tgt = (unsigned)(t + 1);
      for (;;) {
        unsigned v = __hip_atomic_load(&flags[lane * 32], __ATOMIC_RELAXED,
                                       __HIP_MEMORY_SCOPE_AGENT);
        if (__all(v >= tgt)) break;
      }
      asm volatile("" ::: "memory");
    }
    __syncthreads();
  }
}

// ---------------- experts (240 blocks) + eval (8 blocks): pure streaming ----------------
__global__ __launch_bounds__(512) void experts(const float* __restrict__ zpos,
                                               const float* __restrict__ zneg,
                                               const float* __restrict__ agru,
                                               const float* __restrict__ W1,
                                               const float* __restrict__ b_t,
                                               const float* __restrict__ ipo,
                                               const float* __restrict__ eW1,
                                               float* __restrict__ hacc,
                                               float* __restrict__ ehacc,
                                               const int* __restrict__ fptr) {
  const int bid = blockIdx.x;
  const int tid = threadIdx.x;
  const int f   = *fptr;

  if (bid < kF * EXP_PRT) {
    __shared__ float xs_p[256];
    __shared__ float xs_n[256];
    int e = bid >> 3, part = bid & 7;
    if (e >= f) return;

    if (part < 4) {
      // z-half rows [part*256, part*256+256)
      int r0 = part * 256;
      if (tid < 256) {
        xs_p[tid] = zpos[(size_t)e * kZ + r0 + tid];
        xs_n[tid] = zneg[(size_t)e * kZ + r0 + tid];
      }
      __syncthreads();
      float ap = 0.f, an = 0.f;
      const float* w = W1 + ((size_t)e * kDIN + r0) * kDH + tid;
#pragma unroll 8
      for (int r = 0; r < 256; r++) {
        float wv = w[(size_t)r * kDH];
        ap += xs_p[r] * wv;
        an += xs_n[r] * wv;
      }
      hacc[(((size_t)e * 2 + 0) * EXP_PRT + part) * kDH + tid] = ap;
      hacc[(((size_t)e * 2 + 1) * EXP_PRT + part) * kDH + tid] = an;
    } else {
      // agru-half rows [(part-4)*256, ...): pos and neg share this input
      int r0 = (part - 4) * 256;
      if (tid < 256) xs_p[tid] = agent_ld(agru + (size_t)e * kH + r0 + tid);
      __syncthreads();
      float a = 0.f;
      const float* w = W1 + ((size_t)e * kDIN + kZ + r0) * kDH + tid;
#pragma unroll 8
      for (int r = 0; r < 256; r++) a += xs_p[r] * w[(size_t)r * kDH];
      hacc[(((size_t)e * 2 + 0) * EXP_PRT + part) * kDH + tid] = a;
      hacc[(((size_t)e * 2 + 1) * EXP_PRT + part) * kDH + tid] = a;
    }
  } else {
    // eval first layer, 8 partial blocks
    __shared__ float evs[140];
    int part = bid - kF * EXP_PRT;  // 0..7
    int r0 = part * 140;
    int nr = min(140, kEIN - r0);
    if (tid < nr) {
      int r = r0 + tid;
      evs[tid] = (r < kH) ? b_t[r] : ipo[r - kH];
    }
    __syncthreads();
    float acc = 0.f;
    const float* w = eW1 + (size_t)r0 * kEH + tid;
    for (int r = 0; r < nr; r++) acc += evs[r] * w[(size_t)r * kEH];
    ehacc[(size_t)part * kEH + tid] = acc;
  }
}

// ---------------- stage2: second layers -> 2f+94 outputs ----------------
__global__ __launch_bounds__(512) void stage2(const float* __restrict__ hacc,
                                              const float* __restrict__ ehacc,
                                              const float* __restrict__ b1,
                                              const float* __restrict__ W2,
                                              const float* __restrict__ b2,
                                              const float* __restrict__ eb1,
                                              const float* __restrict__ eW2,
                                              const float* __restrict__ eb2,
                                              float* __restrict__ out,
                                              const int* __restrict__ fptr) {
  int b = blockIdx.x;
  int tid = threadIdx.x;
  int f = *fptr;
  if (b < kF) {
    int i = b;
    if (i >= f) return;
    float sp = 0.f, sn = 0.f;
#pragma unroll
    for (int p = 0; p < EXP_PRT; p++) {
      sp += hacc[(((size_t)i * 2 + 0) * EXP_PRT + p) * kDH + tid];
      sn += hacc[(((size_t)i * 2 + 1) * EXP_PRT + p) * kDH + tid];
    }
    float bias = b1[(size_t)i * kDH + tid];
    float hp = fmaxf(sp + bias, 0.f);
    float hn = fmaxf(sn + bias, 0.f);
    float w = W2[(size_t)i * kDH + tid];
    float pp = wave_reduce(hp * w);
    float pn = wave_reduce(hn * w);
    __shared__ float redp[8];
    __shared__ float redn[8];
    int wave = tid >> 6, lane = tid & 63;
    if (lane == 0) { redp[wave] = pp; redn[wave] = pn; }
    __syncthreads();
    if (tid == 0) {
      float s0 = 0.f, s1 = 0.f;
#pragma unroll
      for (int k = 0; k < 8; k++) { s0 += redp[k]; s1 += redn[k]; }
      out[i] = s0 + b2[i];
      out[f + i] = s1 + b2[i];
    }
  } else {
    // eval second layer: reduce 8 partials cooperatively, then 94 outputs
    __shared__ float ehs[kEH];
    {
      float s = eb1[tid];
#pragma unroll
      for (int p = 0; p < 8; p++) s += ehacc[(size_t)p * kEH + tid];
      ehs[tid] = fmaxf(s, 0.f);
    }
    __syncthreads();
    if (tid < kEOUT) {
      float acc = eb2[tid];
      for (int h = 0; h < kEH; h++) acc += ehs[h] * eW2[(size_t)h * kEOUT + tid];
      out[2 * f + tid] = sigmoidf_(acc);
    }
  }
}

extern "C" void kernel_launch(void* const* d_in, const int* in_sizes, int n_in,
                              void* d_out, int out_size, void* d_ws, size_t ws_size,
                              hipStream_t stream) {
  const float* b_t  = (const float*)d_in[0];
  const float* a_t  = (const float*)d_in[1];
  const float* zpos = (const float*)d_in[2];
  const float* zneg = (const float*)d_in[3];
  const float* ipo  = (const float*)d_in[4];
  const float* gWih = (const float*)d_in[5];
  const float* gWhh = (const float*)d_in[6];
  const float* gbih = (const float*)d_in[7];
  const float* gbhh = (const float*)d_in[8];
  const float* mW1  = (const float*)d_in[9];
  const float* mb1  = (const float*)d_in[10];
  const float* mW2  = (const float*)d_in[11];
  const float* mb2  = (const float*)d_in[12];
  const float* eW1  = (const float*)d_in[13];
  const float* eb1  = (const float*)d_in[14];
  const float* eW2  = (const float*)d_in[15];
  const float* eb2  = (const float*)d_in[16];
  const int*   fptr = (const int*)d_in[17];

  float* ws     = (float*)d_ws;
  float* agru   = ws + AGRU_OFF;
  float* hacc   = ws + HACC_OFF;
  float* ehacc  = ws + EHA_OFF;
  unsigned* flg = (unsigned*)(ws + FLG_OFF);
  float* out    = (float*)d_out;

  // only the flag array needs zeroing now (partial sums are fully overwritten)
  hipMemsetAsync(flg, 0, FLG_CNT * sizeof(unsigned), stream);

  // 1) GRU runs alone: latency-critical, fence-free sc1 message passing
  gru64<<<GRU_NB, 512, 0, stream>>>(gWhh, gbhh, gWih, gbih, a_t, b_t, agru, flg, fptr);

  // 2) expert + eval first layers: pure HBM streaming, no waits
  experts<<<kF * EXP_PRT + 8, 512, 0, stream>>>(zpos, zneg, agru, mW1, b_t, ipo, eW1,
                                                hacc, ehacc, fptr);

  // 3) second layers -> outputs
  stage2<<<kF + 1, 512, 0, stream>>>(hacc, ehacc, mb1, mW2, mb2, eb1, eW2, eb2, out, fptr);
}

// Round 6
// 351.474 us; speedup vs baseline: 1.4403x; 1.0101x over previous
//
#include <hip/hip_runtime.h>
#include <math.h>

// ---- problem constants ----
constexpr int kH    = 1024;
constexpr int kZ    = 1024;
constexpr int kA    = 4;
constexpr int kF    = 30;
constexpr int kDIN  = 2048;
constexpr int kDH   = 512;
constexpr int kEIN  = 1118;
constexpr int kEH   = 512;
constexpr int kEOUT = 94;

constexpr int GRU_NB  = 64;   // GRU blocks
constexpr int EXP_PRT = 8;    // partial-sum splits per expert (256 K-rows each)

// workspace layout (floats; TAG region is 8-byte packed h+tag, poison-safe:
// tag values 1..30 can never equal the 0xAAAAAAAA poison, so NO memset needed)
constexpr size_t AGRU_OFF = 0;                                          // kF*kH
constexpr size_t HACC_OFF = AGRU_OFF + (size_t)kF * kH;                 // kF*2*8*kDH
constexpr size_t EHA_OFF  = HACC_OFF + (size_t)kF * 2 * EXP_PRT * kDH;  // 8*kEH
constexpr size_t TAG_OFF  = EHA_OFF + (size_t)8 * kEH;                  // kF*kH ull (even float off)

__device__ __forceinline__ float sigmoidf_(float x) { return 1.0f / (1.0f + __expf(-x)); }

__device__ __forceinline__ float wave_reduce(float v) {
#pragma unroll
  for (int off = 32; off > 0; off >>= 1) v += __shfl_down(v, off, 64);
  return v;
}

__device__ __forceinline__ unsigned long long tag_ld(const unsigned long long* p) {
  return __hip_atomic_load(p, __ATOMIC_RELAXED, __HIP_MEMORY_SCOPE_AGENT);
}
__device__ __forceinline__ void tag_st(unsigned long long* p, unsigned long long v) {
  __hip_atomic_store(p, v, __ATOMIC_RELAXED, __HIP_MEMORY_SCOPE_AGENT);
}

// ---------------- GRU: 64 blocks; h exchanged as self-validating (tag|value) ----------------
__global__ __launch_bounds__(512) void gru64(const float* __restrict__ Whh,
                                             const float* __restrict__ bhh,
                                             const float* __restrict__ Wih,
                                             const float* __restrict__ bih,
                                             const float* __restrict__ a_t,
                                             const float* __restrict__ b_t,
                                             float* __restrict__ agru,
                                             unsigned long long* __restrict__ tagbuf,
                                             const int* __restrict__ fptr) {
  const int bid  = blockIdx.x;
  const int tid  = threadIdx.x;
  const int wave = tid >> 6;
  const int lane = tid & 63;
  const int f    = *fptr;

  const int jb = bid * 16;
  const int j0 = jb + wave;       // rows j0 and j1 = j0+8
  const int j1 = jb + wave + 8;

  __shared__ float gis[kF][16][3];
  __shared__ __align__(16) float hs[kH];

  const float4* W4 = (const float4*)Whh;
  float4 wr0[4], wz0[4], wn0[4], wr1[4], wz1[4], wn1[4];
#pragma unroll
  for (int i = 0; i < 4; i++) {
    wr0[i] = W4[(size_t)j0 * 256 + i * 64 + lane];
    wz0[i] = W4[(size_t)(j0 + kH) * 256 + i * 64 + lane];
    wn0[i] = W4[(size_t)(j0 + 2 * kH) * 256 + i * 64 + lane];
    wr1[i] = W4[(size_t)j1 * 256 + i * 64 + lane];
    wz1[i] = W4[(size_t)(j1 + kH) * 256 + i * 64 + lane];
    wn1[i] = W4[(size_t)(j1 + 2 * kH) * 256 + i * 64 + lane];
  }
  const float b0r = bhh[j0], b0z = bhh[j0 + kH], b0n = bhh[j0 + 2 * kH];
  const float b1r = bhh[j1], b1z = bhh[j1 + kH], b1n = bhh[j1 + 2 * kH];

  // gi[t][w][g] for this block's 16 rows (off critical path)
  for (int idx = tid; idx < kF * 16 * 3; idx += 512) {
    int t = idx / 48;
    int rem = idx - t * 48;
    int w = rem / 3, g = rem - w * 3;
    int r = jb + w + g * kH;
    float acc = bih[r];
    const float* wih = Wih + (size_t)r * kA;
    const float* at  = a_t + (size_t)t * kA;
#pragma unroll
    for (int k = 0; k < kA; k++) acc += wih[k] * at[k];
    gis[t][w][g] = acc;
  }
  __syncthreads();

  const float4* hs4 = (const float4*)hs;
  for (int t = 0; t < f; t++) {
    // ---- acquire h_{t-1}: poll the tagged data directly (1 L3 round trip) ----
    if (t == 0) {
      hs[tid]       = b_t[tid];
      hs[tid + 512] = b_t[tid + 512];
    } else {
      const unsigned long long* tg = tagbuf + (size_t)(t - 1) * kH;
      const unsigned want = (unsigned)t;  // step t-1 wrote tag t
      unsigned long long v0 = tag_ld(tg + tid);
      unsigned long long v1 = tag_ld(tg + tid + 512);
      while ((unsigned)(v0 >> 32) != want) v0 = tag_ld(tg + tid);
      while ((unsigned)(v1 >> 32) != want) v1 = tag_ld(tg + tid + 512);
      hs[tid]       = __uint_as_float((unsigned)v0);
      hs[tid + 512] = __uint_as_float((unsigned)v1);
    }
    __syncthreads();

    // ---- compute this block's 16 rows ----
    float a0r = 0.f, a0z = 0.f, a0n = 0.f, a1r = 0.f, a1z = 0.f, a1n = 0.f;
#pragma unroll
    for (int i = 0; i < 4; i++) {
      float4 h4 = hs4[i * 64 + lane];
      a0r += wr0[i].x * h4.x + wr0[i].y * h4.y + wr0[i].z * h4.z + wr0[i].w * h4.w;
      a0z += wz0[i].x * h4.x + wz0[i].y * h4.y + wz0[i].z * h4.z + wz0[i].w * h4.w;
      a0n += wn0[i].x * h4.x + wn0[i].y * h4.y + wn0[i].z * h4.z + wn0[i].w * h4.w;
      a1r += wr1[i].x * h4.x + wr1[i].y * h4.y + wr1[i].z * h4.z + wr1[i].w * h4.w;
      a1z += wz1[i].x * h4.x + wz1[i].y * h4.y + wz1[i].z * h4.z + wz1[i].w * h4.w;
      a1n += wn1[i].x * h4.x + wn1[i].y * h4.y + wn1[i].z * h4.z + wn1[i].w * h4.w;
    }
    a0r = wave_reduce(a0r); a0z = wave_reduce(a0z); a0n = wave_reduce(a0n);
    a1r = wave_reduce(a1r); a1z = wave_reduce(a1z); a1n = wave_reduce(a1n);

    if (lane == 0) {
      float rg = sigmoidf_(gis[t][wave][0] + a0r + b0r);
      float zg = sigmoidf_(gis[t][wave][1] + a0z + b0z);
      float ng = tanhf(gis[t][wave][2] + rg * (a0n + b0n));
      float h0 = (1.0f - zg) * ng + zg * hs[j0];
      rg = sigmoidf_(gis[t][wave + 8][0] + a1r + b1r);
      zg = sigmoidf_(gis[t][wave + 8][1] + a1z + b1z);
      ng = tanhf(gis[t][wave + 8][2] + rg * (a1n + b1n));
      float h1 = (1.0f - zg) * ng + zg * hs[j1];

      const unsigned long long tg = (unsigned long long)(unsigned)(t + 1) << 32;
      // fire-and-forget: tagged copy for GRU peers (self-validating) ...
      tag_st(tagbuf + (size_t)t * kH + j0, tg | (unsigned long long)__float_as_uint(h0));
      tag_st(tagbuf + (size_t)t * kH + j1, tg | (unsigned long long)__float_as_uint(h1));
      // ... and plain copy for the experts kernel (visible via kernel-boundary release)
      agru[(size_t)t * kH + j0] = h0;
      agru[(size_t)t * kH + j1] = h1;
    }
    __syncthreads();  // all waves done reading hs before next-step refill
  }
}

// ---------------- experts (240 blocks) + eval (8 blocks): pure streaming ----------------
__global__ __launch_bounds__(512) void experts(const float* __restrict__ zpos,
                                               const float* __restrict__ zneg,
                                               const float* __restrict__ agru,
                                               const float* __restrict__ W1,
                                               const float* __restrict__ b_t,
                                               const float* __restrict__ ipo,
                                               const float* __restrict__ eW1,
                                               float* __restrict__ hacc,
                                               float* __restrict__ ehacc,
                                               const int* __restrict__ fptr) {
  const int bid = blockIdx.x;
  const int tid = threadIdx.x;
  const int f   = *fptr;

  if (bid < kF * EXP_PRT) {
    __shared__ float xs_p[256];
    __shared__ float xs_n[256];
    int e = bid >> 3, part = bid & 7;
    if (e >= f) return;

    if (part < 4) {
      // z-half rows [part*256, part*256+256)
      int r0 = part * 256;
      if (tid < 256) {
        xs_p[tid] = zpos[(size_t)e * kZ + r0 + tid];
        xs_n[tid] = zneg[(size_t)e * kZ + r0 + tid];
      }
      __syncthreads();
      float ap = 0.f, an = 0.f;
      const float* w = W1 + ((size_t)e * kDIN + r0) * kDH + tid;
#pragma unroll 8
      for (int r = 0; r < 256; r++) {
        float wv = w[(size_t)r * kDH];
        ap += xs_p[r] * wv;
        an += xs_n[r] * wv;
      }
      hacc[(((size_t)e * 2 + 0) * EXP_PRT + part) * kDH + tid] = ap;
      hacc[(((size_t)e * 2 + 1) * EXP_PRT + part) * kDH + tid] = an;
    } else {
      // agru-half rows [(part-4)*256, ...): pos and neg share this input
      int r0 = (part - 4) * 256;
      if (tid < 256) xs_p[tid] = agru[(size_t)e * kH + r0 + tid];
      __syncthreads();
      float a = 0.f;
      const float* w = W1 + ((size_t)e * kDIN + kZ + r0) * kDH + tid;
#pragma unroll 8
      for (int r = 0; r < 256; r++) a += xs_p[r] * w[(size_t)r * kDH];
      hacc[(((size_t)e * 2 + 0) * EXP_PRT + part) * kDH + tid] = a;
      hacc[(((size_t)e * 2 + 1) * EXP_PRT + part) * kDH + tid] = a;
    }
  } else {
    // eval first layer, 8 partial blocks
    __shared__ float evs[140];
    int part = bid - kF * EXP_PRT;  // 0..7
    int r0 = part * 140;
    int nr = min(140, kEIN - r0);
    if (tid < nr) {
      int r = r0 + tid;
      evs[tid] = (r < kH) ? b_t[r] : ipo[r - kH];
    }
    __syncthreads();
    float acc = 0.f;
    const float* w = eW1 + (size_t)r0 * kEH + tid;
    for (int r = 0; r < nr; r++) acc += evs[r] * w[(size_t)r * kEH];
    ehacc[(size_t)part * kEH + tid] = acc;
  }
}

// ---------------- stage2: second layers -> 2f+94 outputs ----------------
__global__ __launch_bounds__(512) void stage2(const float* __restrict__ hacc,
                                              const float* __restrict__ ehacc,
                                              const float* __restrict__ b1,
                                              const float* __restrict__ W2,
                                              const float* __restrict__ b2,
                                              const float* __restrict__ eb1,
                                              const float* __restrict__ eW2,
                                              const float* __restrict__ eb2,
                                              float* __restrict__ out,
                                              const int* __restrict__ fptr) {
  int b = blockIdx.x;
  int tid = threadIdx.x;
  int f = *fptr;
  if (b < kF) {
    int i = b;
    if (i >= f) return;
    float sp = 0.f, sn = 0.f;
#pragma unroll
    for (int p = 0; p < EXP_PRT; p++) {
      sp += hacc[(((size_t)i * 2 + 0) * EXP_PRT + p) * kDH + tid];
      sn += hacc[(((size_t)i * 2 + 1) * EXP_PRT + p) * kDH + tid];
    }
    float bias = b1[(size_t)i * kDH + tid];
    float hp = fmaxf(sp + bias, 0.f);
    float hn = fmaxf(sn + bias, 0.f);
    float w = W2[(size_t)i * kDH + tid];
    float pp = wave_reduce(hp * w);
    float pn = wave_reduce(hn * w);
    __shared__ float redp[8];
    __shared__ float redn[8];
    int wave = tid >> 6, lane = tid & 63;
    if (lane == 0) { redp[wave] = pp; redn[wave] = pn; }
    __syncthreads();
    if (tid == 0) {
      float s0 = 0.f, s1 = 0.f;
#pragma unroll
      for (int k = 0; k < 8; k++) { s0 += redp[k]; s1 += redn[k]; }
      out[i] = s0 + b2[i];
      out[f + i] = s1 + b2[i];
    }
  } else {
    // eval second layer: reduce 8 partials cooperatively, then 94 outputs
    __shared__ float ehs[kEH];
    {
      float s = eb1[tid];
#pragma unroll
      for (int p = 0; p < 8; p++) s += ehacc[(size_t)p * kEH + tid];
      ehs[tid] = fmaxf(s, 0.f);
    }
    __syncthreads();
    if (tid < kEOUT) {
      float acc = eb2[tid];
      for (int h = 0; h < kEH; h++) acc += ehs[h] * eW2[(size_t)h * kEOUT + tid];
      out[2 * f + tid] = sigmoidf_(acc);
    }
  }
}

extern "C" void kernel_launch(void* const* d_in, const int* in_sizes, int n_in,
                              void* d_out, int out_size, void* d_ws, size_t ws_size,
                              hipStream_t stream) {
  const float* b_t  = (const float*)d_in[0];
  const float* a_t  = (const float*)d_in[1];
  const float* zpos = (const float*)d_in[2];
  const float* zneg = (const float*)d_in[3];
  const float* ipo  = (const float*)d_in[4];
  const float* gWih = (const float*)d_in[5];
  const float* gWhh = (const float*)d_in[6];
  const float* gbih = (const float*)d_in[7];
  const float* gbhh = (const float*)d_in[8];
  const float* mW1  = (const float*)d_in[9];
  const float* mb1  = (const float*)d_in[10];
  const float* mW2  = (const float*)d_in[11];
  const float* mb2  = (const float*)d_in[12];
  const float* eW1  = (const float*)d_in[13];
  const float* eb1  = (const float*)d_in[14];
  const float* eW2  = (const float*)d_in[15];
  const float* eb2  = (const float*)d_in[16];
  const int*   fptr = (const int*)d_in[17];

  float* ws     = (float*)d_ws;
  float* agru   = ws + AGRU_OFF;
  float* hacc   = ws + HACC_OFF;
  float* ehacc  = ws + EHA_OFF;
  unsigned long long* tagbuf = (unsigned long long*)(ws + TAG_OFF);
  float* out    = (float*)d_out;

  // NO memset needed: tag values 1..30 are distinguishable from 0xAA poison,
  // and all partial-sum slots are fully overwritten before being read.

  // 1) GRU: latency-critical, self-validating tagged h exchange (1 RT/step)
  gru64<<<GRU_NB, 512, 0, stream>>>(gWhh, gbhh, gWih, gbih, a_t, b_t, agru, tagbuf, fptr);

  // 2) expert + eval first layers: pure HBM streaming, no waits
  experts<<<kF * EXP_PRT + 8, 512, 0, stream>>>(zpos, zneg, agru, mW1, b_t, ipo, eW1,
                                                hacc, ehacc, fptr);

  // 3) second layers -> outputs
  stage2<<<kF + 1, 512, 0, stream>>>(hacc, ehacc, mb1, mW2, mb2, eb1, eW2, eb2, out, fptr);
}